// Round 21
// baseline (31.728 us; speedup 1.0000x reference)
//
#include <hip/hip_runtime.h>
#include <hip/hip_bf16.h>
#include <math.h>

// Problem: B=16, K=256, D=128, H=64
//   sd[b,i,j] = sum_h gelu(hi[b,i,h] + hj[b,j,h]) * W2[h] + b2,  loss = MSE vs dist
//
// Measured ledger:
//  R7: fence storm +90us. R10: pk_f32 rate-neutral (2 passes). R13: trans ops
//  occupy VALU. R15: kA~4.5 kB~15.5 kC~0.5 gaps~6.5. R19/R20: tile/VGPR neutral.
//  R21: pk_f16 IS rate-positive (2 elems in one 32b reg, one 2-cyc issue).
//  Full gelu chain in packed f16 asm: f16 Schraudolph exp2 + f16 magic-rcp
//  (sign baked: 0xF799 -> acc holds -sum, sd = b2 - acc) + v_dot2_f32_f16.
//  15 ops/2elem = 7.5cyc/elem (was 18); LDS traffic and h-loop iters halve.

#define Bn 16
#define Kn 256
#define Dn 128
#define Hn 64
#define NBLK 1024    // kB grid: 8 x 8 x 16

typedef unsigned int uint32;

// Packed-f16 gelu pair: acc -= gelu(a.l+c.l)*w.l + gelu(a.h+c.h)*w.h  (f32 acc)
//   gelu(x) ~= x * sigmoid(1.702x); e^{-1.702x} = 2^{-2.4555x} via f16
//   Schraudolph: u = fma(x, -2514.4, 15315.4) [=1024*(t+15-0.0436)], clamp
//   x>=-5.7 (u<=29647<i16max) and u>=0 (x>6.09 -> sigma=1 -> g=x exact).
//   i16(u) bits reinterpreted as f16 = ~2^t. Magic rcp 0xF799 with sign baked
//   (R10): nr = -r0; after NR, m = -1/d; g = -x*sigma; dot2 accumulates -sum.
__device__ __forceinline__ void gelu_pair(uint32 a, uint32 c, uint32 w, float& acc,
                                          uint32 kXLO, uint32 kK1, uint32 kK2,
                                          uint32 kZERO, uint32 kONE, uint32 kTWO,
                                          uint32 kNMG) {
    uint32 x, xc, u, uc, uh, i0, i0m, i1, e, d, nr, q, m, g;
    asm("v_pk_add_f16 %0, %1, %2"      : "=v"(x)   : "v"(a),  "v"(c));
    asm("v_pk_max_f16 %0, %1, %2"      : "=v"(xc)  : "v"(x),  "v"(kXLO));
    asm("v_pk_fma_f16 %0, %1, %2, %3"  : "=v"(u)   : "v"(xc), "v"(kK1), "v"(kK2));
    asm("v_pk_max_f16 %0, %1, %2"      : "=v"(uc)  : "v"(u),  "v"(kZERO));
    asm("v_lshrrev_b32 %0, 16, %1"     : "=v"(uh)  : "v"(uc));
    asm("v_cvt_i16_f16 %0, %1"         : "=v"(i0)  : "v"(uc));
    asm("v_and_b32 %0, 0xffff, %1"     : "=v"(i0m) : "v"(i0));
    asm("v_cvt_i16_f16 %0, %1"         : "=v"(i1)  : "v"(uh));
    asm("v_lshl_or_b32 %0, %1, 16, %2" : "=v"(e)   : "v"(i1), "v"(i0m));
    asm("v_pk_add_f16 %0, %1, %2"      : "=v"(d)   : "v"(e),  "v"(kONE));
    asm("v_pk_sub_u16 %0, %1, %2"      : "=v"(nr)  : "v"(kNMG), "v"(d));
    asm("v_pk_fma_f16 %0, %1, %2, %3"  : "=v"(q)   : "v"(d),  "v"(nr), "v"(kTWO));
    asm("v_pk_mul_f16 %0, %1, %2"      : "=v"(m)   : "v"(nr), "v"(q));
    asm("v_pk_mul_f16 %0, %1, %2"      : "=v"(g)   : "v"(xc), "v"(m));
    asm("v_dot2_f32_f16 %0, %1, %2, %0" : "+v"(acc) : "v"(g), "v"(w));
}

__device__ __forceinline__ unsigned short f16b(float v) {
    _Float16 h = (_Float16)v;
    return __builtin_bit_cast(unsigned short, h);
}

// ---------------- Kernel A: hi/hj precompute (f32 math, f16 store) ----------------
// 1024 blocks x 64 threads; lane = h; block = 4 rows (R16 structure).
__global__ __launch_bounds__(64) void kA(const float* __restrict__ particles,
                                         const float* __restrict__ W1,
                                         const float* __restrict__ b1,
                                         unsigned short* __restrict__ hi,
                                         unsigned short* __restrict__ hj) {
    const int hg  = threadIdx.x;               // 0..63
    const int row = blockIdx.x * 4;

    const float* __restrict__ p0 = particles + (size_t)row * Dn;
    const float* __restrict__ p1 = p0 + Dn;
    const float* __restrict__ p2 = p0 + 2 * Dn;
    const float* __restrict__ p3 = p0 + 3 * Dn;
    const float* __restrict__ wa = W1 + hg;
    const float* __restrict__ wb = W1 + Dn * Hn + hg;

    float ai0 = 0.f, ai1 = 0.f, ai2 = 0.f, ai3 = 0.f;
    float aj0 = 0.f, aj1 = 0.f, aj2 = 0.f, aj3 = 0.f;
#pragma unroll 8
    for (int d = 0; d < Dn; ++d) {
        const float va = wa[(size_t)d * Hn];
        const float vb = wb[(size_t)d * Hn];
        const float pa = p0[d];
        const float pb = p1[d];
        const float pc = p2[d];
        const float pd = p3[d];
        ai0 = fmaf(pa, va, ai0); aj0 = fmaf(pa, vb, aj0);
        ai1 = fmaf(pb, va, ai1); aj1 = fmaf(pb, vb, aj1);
        ai2 = fmaf(pc, va, ai2); aj2 = fmaf(pc, vb, aj2);
        ai3 = fmaf(pd, va, ai3); aj3 = fmaf(pd, vb, aj3);
    }
    const float bh = b1[hg];
    hi[(size_t)(row + 0) * Hn + hg] = f16b(ai0 + bh);
    hi[(size_t)(row + 1) * Hn + hg] = f16b(ai1 + bh);
    hi[(size_t)(row + 2) * Hn + hg] = f16b(ai2 + bh);
    hi[(size_t)(row + 3) * Hn + hg] = f16b(ai3 + bh);
    hj[(size_t)(row + 0) * Hn + hg] = f16b(aj0);
    hj[(size_t)(row + 1) * Hn + hg] = f16b(aj1);
    hj[(size_t)(row + 2) * Hn + hg] = f16b(aj2);
    hj[(size_t)(row + 3) * Hn + hg] = f16b(aj3);
}

// ---------------- Kernel B: 32x32 tile, 4 outputs/thread, packed-f16 gelu ----------------
// grid (8,8,16), 256 threads, launch_bounds(256,4). Staging f16: rows 64 f16 =
// 128B = 8 uint4; pad stride 72 f16 (144B -> shj rows spread banks 0,4..28,
// 2-way = free). h-loop: 8 iters x 8h; per iter 4 ds_read_b128 + 16 gelu_pair.
__global__ __launch_bounds__(256, 4) void kB(const unsigned short* __restrict__ hi,
                                             const unsigned short* __restrict__ hj,
                                             const float* __restrict__ positions,
                                             const float* __restrict__ W2,
                                             const float* __restrict__ b2,
                                             float* __restrict__ out,
                                             float* __restrict__ partials) {
    __shared__ __align__(16) unsigned short shi[32][72];
    __shared__ __align__(16) unsigned short shj[32][72];
    __shared__ float pix[32], piy[32], pjx[32], pjy[32];
    __shared__ float wsum[4];

    const int jt = blockIdx.x, it = blockIdx.y, b = blockIdx.z;
    const int tid = threadIdx.x;
    const int bi = b * Kn + it * 32;
    const int bj = b * Kn + jt * 32;

    {   // stage: 256 uint4 per tile, 1 per thread each
        const int rr = tid >> 3, q8 = (tid & 7) * 8;
        *(uint4*)&shi[rr][q8] = *(const uint4*)&hi[(size_t)(bi + rr) * Hn + q8];
        *(uint4*)&shj[rr][q8] = *(const uint4*)&hj[(size_t)(bj + rr) * Hn + q8];
    }
    if (tid < 32) {
        pix[tid] = positions[(bi + tid) * 2 + 0];
        piy[tid] = positions[(bi + tid) * 2 + 1];
        pjx[tid] = positions[(bj + tid) * 2 + 0];
        pjy[tid] = positions[(bj + tid) * 2 + 1];
    }
    const float bb = b2[0];

    // W2 -> 32 packed-f16 registers (uniform loads; once per thread)
    uint32 wreg[32];
#pragma unroll
    for (int q = 0; q < 32; ++q) {
        const float2 wp = ((const float2*)W2)[q];
        wreg[q] = (uint32)f16b(wp.x) | ((uint32)f16b(wp.y) << 16);
    }

    // f16x2 constants (replicated halves)
    const uint32 kXLO = 0xC5B3C5B3u;   // -5.7
    const uint32 kK1  = 0xE8E9E8E9u;   // -2514.4  (-2.4555*1024)
    const uint32 kK2  = 0x737A737Au;   // 15315.4  ((15-0.0436)*1024)
    const uint32 kZERO= 0x00000000u;
    const uint32 kONE = 0x3C003C00u;   // 1.0
    const uint32 kTWO = 0x40004000u;   // 2.0
    const uint32 kNMG = 0xF799F799u;   // rcp magic 0x7799 with sign baked (-r0)

    __syncthreads();

    const int ti = tid >> 4, tj = tid & 15;

    float acc00 = 0.f, acc01 = 0.f, acc10 = 0.f, acc11 = 0.f;
#pragma unroll
    for (int it8 = 0; it8 < 8; ++it8) {
        const int h = it8 * 8;
        const uint4 a0 = *(const uint4*)&shi[ti][h];
        const uint4 a1 = *(const uint4*)&shi[ti + 16][h];
        const uint4 c0 = *(const uint4*)&shj[tj][h];
        const uint4 c1 = *(const uint4*)&shj[tj + 16][h];
        const uint32 w0 = wreg[it8 * 4 + 0], w1 = wreg[it8 * 4 + 1];
        const uint32 w2 = wreg[it8 * 4 + 2], w3 = wreg[it8 * 4 + 3];
        gelu_pair(a0.x, c0.x, w0, acc00, kXLO, kK1, kK2, kZERO, kONE, kTWO, kNMG);
        gelu_pair(a0.y, c0.y, w1, acc00, kXLO, kK1, kK2, kZERO, kONE, kTWO, kNMG);
        gelu_pair(a0.z, c0.z, w2, acc00, kXLO, kK1, kK2, kZERO, kONE, kTWO, kNMG);
        gelu_pair(a0.w, c0.w, w3, acc00, kXLO, kK1, kK2, kZERO, kONE, kTWO, kNMG);
        gelu_pair(a0.x, c1.x, w0, acc01, kXLO, kK1, kK2, kZERO, kONE, kTWO, kNMG);
        gelu_pair(a0.y, c1.y, w1, acc01, kXLO, kK1, kK2, kZERO, kONE, kTWO, kNMG);
        gelu_pair(a0.z, c1.z, w2, acc01, kXLO, kK1, kK2, kZERO, kONE, kTWO, kNMG);
        gelu_pair(a0.w, c1.w, w3, acc01, kXLO, kK1, kK2, kZERO, kONE, kTWO, kNMG);
        gelu_pair(a1.x, c0.x, w0, acc10, kXLO, kK1, kK2, kZERO, kONE, kTWO, kNMG);
        gelu_pair(a1.y, c0.y, w1, acc10, kXLO, kK1, kK2, kZERO, kONE, kTWO, kNMG);
        gelu_pair(a1.z, c0.z, w2, acc10, kXLO, kK1, kK2, kZERO, kONE, kTWO, kNMG);
        gelu_pair(a1.w, c0.w, w3, acc10, kXLO, kK1, kK2, kZERO, kONE, kTWO, kNMG);
        gelu_pair(a1.x, c1.x, w0, acc11, kXLO, kK1, kK2, kZERO, kONE, kTWO, kNMG);
        gelu_pair(a1.y, c1.y, w1, acc11, kXLO, kK1, kK2, kZERO, kONE, kTWO, kNMG);
        gelu_pair(a1.z, c1.z, w2, acc11, kXLO, kK1, kK2, kZERO, kONE, kTWO, kNMG);
        gelu_pair(a1.w, c1.w, w3, acc11, kXLO, kK1, kK2, kZERO, kONE, kTWO, kNMG);
    }
    // acc holds -sum(gelu*w): fold sign out
    const float sd00 = bb - acc00, sd01 = bb - acc01;
    const float sd10 = bb - acc10, sd11 = bb - acc11;

    const float xi0 = pix[ti], yi0 = piy[ti], xi1 = pix[ti + 16], yi1 = piy[ti + 16];
    const float xj0 = pjx[tj], yj0 = pjy[tj], xj1 = pjx[tj + 16], yj1 = pjy[tj + 16];
    const float d200 = (xi0-xj0)*(xi0-xj0) + (yi0-yj0)*(yi0-yj0);
    const float d201 = (xi0-xj1)*(xi0-xj1) + (yi0-yj1)*(yi0-yj1);
    const float d210 = (xi1-xj0)*(xi1-xj0) + (yi1-yj0)*(yi1-yj0);
    const float d211 = (xi1-xj1)*(xi1-xj1) + (yi1-yj1)*(yi1-yj1);
    const float td00 = (d200 > 0.f) ? sqrtf(d200) : 0.f;
    const float td01 = (d201 > 0.f) ? sqrtf(d201) : 0.f;
    const float td10 = (d210 > 0.f) ? sqrtf(d210) : 0.f;
    const float td11 = (d211 > 0.f) ? sqrtf(d211) : 0.f;

    const int i0 = it * 32 + ti, i1 = i0 + 16;
    const int j0 = jt * 32 + tj, j1 = j0 + 16;
    out[((b * Kn) + i0) * Kn + j0] = sd00;
    out[((b * Kn) + i0) * Kn + j1] = sd01;
    out[((b * Kn) + i1) * Kn + j0] = sd10;
    out[((b * Kn) + i1) * Kn + j1] = sd11;

    // deterministic block reduce of squared error (4 outputs)
    float v = (sd00 - td00) * (sd00 - td00) + (sd01 - td01) * (sd01 - td01)
            + (sd10 - td10) * (sd10 - td10) + (sd11 - td11) * (sd11 - td11);
#pragma unroll
    for (int off = 32; off > 0; off >>= 1) v += __shfl_down(v, off);
    if ((tid & 63) == 0) wsum[tid >> 6] = v;
    __syncthreads();
    if (tid == 0) {
        const int bid = (b * gridDim.y + it) * gridDim.x + jt;
        partials[bid] = (wsum[0] + wsum[1]) + (wsum[2] + wsum[3]);
    }
}

// ---------------- Kernel C: final loss reduction (deterministic order) ----------------
__global__ __launch_bounds__(256) void kC(const float* __restrict__ partials,
                                          float* __restrict__ loss_out) {
    __shared__ float s[256];
    const int tid = threadIdx.x;
    const float4* p4 = (const float4*)partials;        // NBLK/4 = 256 float4
    const float4 x = p4[tid];
    s[tid] = (x.x + x.y) + (x.z + x.w);
    __syncthreads();
    for (int off = 128; off > 0; off >>= 1) {
        if (tid < off) s[tid] += s[tid + off];
        __syncthreads();
    }
    if (tid == 0)
        loss_out[0] = s[0] * (1.0f / (float)(Bn * Kn * Kn));
}

extern "C" void kernel_launch(void* const* d_in, const int* in_sizes, int n_in,
                              void* d_out, int out_size, void* d_ws, size_t ws_size,
                              hipStream_t stream) {
    const float* particles = (const float*)d_in[0];
    const float* positions = (const float*)d_in[1];
    const float* W1        = (const float*)d_in[2];
    const float* b1        = (const float*)d_in[3];
    const float* W2        = (const float*)d_in[4];
    const float* b2        = (const float*)d_in[5];

    float* out = (float*)d_out;                       // [B*K*K] sd, then [1] loss
    unsigned short* hi16 = (unsigned short*)d_ws;               // B*K*H f16
    unsigned short* hj16 = hi16 + (size_t)Bn * Kn * Hn;         // B*K*H f16
    float* partials = (float*)(hj16 + (size_t)Bn * Kn * Hn);    // NBLK floats

    kA<<<dim3((Bn * Kn) / 4), dim3(64), 0, stream>>>(particles, W1, b1, hi16, hj16);
    kB<<<dim3(Kn / 32, Kn / 32, Bn), dim3(256), 0, stream>>>(hi16, hj16, positions, W2, b2,
                                                             out, partials);
    kC<<<dim3(1), dim3(256), 0, stream>>>(partials, out + (size_t)Bn * Kn * Kn);
}

// Round 22
// 27.401 us; speedup vs baseline: 1.1579x; 1.1579x over previous
//
#include <hip/hip_runtime.h>
#include <hip/hip_bf16.h>
#include <math.h>

// Problem: B=16, K=256, D=128, H=64
//   sd[b,i,j] = sum_h gelu(hi[b,i,h] + hj[b,j,h]) * W2[h] + b2,  loss = MSE vs dist
//
// Measured ledger (22 rounds):
//  R7:  device-fence storm = +90us -> loss stays separate kernel kC.
//  R10: pk f32 = scalar FLOP rate (2 passes). R13: v_rcp occupies VALU.
//  R15: kA~4.5 (traffic/TLP trap; R11/R14/R16 variants all equal), kB~15.5,
//       kC~0.5, gaps~6.5.
//  R19: 8-out tile regressed. R20: VGPR128+W2-in-reg = best (27.34us).
//  R21: packed-f16 asm gelu regressed (31.7; serial 15-op asm chain).
//  R22: REVERT to R20 exactly (measured best).

#define Bn 16
#define Kn 256
#define Dn 128
#define Hn 64
#define NBLK 1024    // kB grid: 8 x 8 x 16

// gelu(x) ~= x * sigmoid(1.702 x); Schraudolph exp2 bits + magic-rcp + 1 NR.
// 9 VALU ops per element incl. caller's x-add and the acc fma.
__device__ __forceinline__ void gelu_acc(float x, float w, float& acc) {
    float u  = fmaf(x, -20598733.0f, 1064987473.0f);
    int   iu = (int)u;
    float e  = __builtin_bit_cast(float, iu);
    float d  = e + 1.0f;
    int   ir = 0x7EF311C3 - __builtin_bit_cast(int, d);
    float r0 = __builtin_bit_cast(float, ir);
    float r  = r0 * fmaf(-d, r0, 2.0f);
    acc = fmaf(x * r, w, acc);
}

// ---------------- Kernel A: hi/hj precompute, LDS-free, 4 rows/wave (R16) ----------------
__global__ __launch_bounds__(64) void kA(const float* __restrict__ particles,
                                         const float* __restrict__ W1,
                                         const float* __restrict__ b1,
                                         float* __restrict__ hi,
                                         float* __restrict__ hj) {
    const int hg  = threadIdx.x;               // 0..63
    const int row = blockIdx.x * 4;

    const float* __restrict__ p0 = particles + (size_t)row * Dn;
    const float* __restrict__ p1 = p0 + Dn;
    const float* __restrict__ p2 = p0 + 2 * Dn;
    const float* __restrict__ p3 = p0 + 3 * Dn;
    const float* __restrict__ wa = W1 + hg;
    const float* __restrict__ wb = W1 + Dn * Hn + hg;

    float ai0 = 0.f, ai1 = 0.f, ai2 = 0.f, ai3 = 0.f;
    float aj0 = 0.f, aj1 = 0.f, aj2 = 0.f, aj3 = 0.f;
#pragma unroll 8
    for (int d = 0; d < Dn; ++d) {
        const float va = wa[(size_t)d * Hn];
        const float vb = wb[(size_t)d * Hn];
        const float pa = p0[d];
        const float pb = p1[d];
        const float pc = p2[d];
        const float pd = p3[d];
        ai0 = fmaf(pa, va, ai0); aj0 = fmaf(pa, vb, aj0);
        ai1 = fmaf(pb, va, ai1); aj1 = fmaf(pb, vb, aj1);
        ai2 = fmaf(pc, va, ai2); aj2 = fmaf(pc, vb, aj2);
        ai3 = fmaf(pd, va, ai3); aj3 = fmaf(pd, vb, aj3);
    }
    const float bh = b1[hg];
    hi[(size_t)(row + 0) * Hn + hg] = ai0 + bh;
    hi[(size_t)(row + 1) * Hn + hg] = ai1 + bh;
    hi[(size_t)(row + 2) * Hn + hg] = ai2 + bh;
    hi[(size_t)(row + 3) * Hn + hg] = ai3 + bh;
    hj[(size_t)(row + 0) * Hn + hg] = aj0;
    hj[(size_t)(row + 1) * Hn + hg] = aj1;
    hj[(size_t)(row + 2) * Hn + hg] = aj2;
    hj[(size_t)(row + 3) * Hn + hg] = aj3;
}

// ---------------- Kernel B: 32x32 tile, 4 outputs/thread, wide VGPR budget ----------------
// grid (K/32, K/32, B) = (8,8,16), 256 threads; launch_bounds(256,4):
// 4 waves/SIMD min -> up to 128 VGPRs -> W2 lives in 16 float4 registers.
__global__ __launch_bounds__(256, 4) void kB(const float* __restrict__ hi,
                                             const float* __restrict__ hj,
                                             const float* __restrict__ positions,
                                             const float* __restrict__ W2,
                                             const float* __restrict__ b2,
                                             float* __restrict__ out,
                                             float* __restrict__ partials) {
    __shared__ __align__(16) float shi[32][68];
    __shared__ __align__(16) float shj[32][68];
    __shared__ float pix[32], piy[32], pjx[32], pjy[32];
    __shared__ float wsum[4];

    const int jt = blockIdx.x, it = blockIdx.y, b = blockIdx.z;
    const int tid = threadIdx.x;
    const int bi = b * Kn + it * 32;
    const int bj = b * Kn + jt * 32;

    for (int idx = tid; idx < 512; idx += 256) {
        const int rr = idx >> 4, c4 = (idx & 15) * 4;
        *(float4*)&shi[rr][c4] = *(const float4*)&hi[(bi + rr) * Hn + c4];
        *(float4*)&shj[rr][c4] = *(const float4*)&hj[(bj + rr) * Hn + c4];
    }
    if (tid < 32) {
        pix[tid] = positions[(bi + tid) * 2 + 0];
        piy[tid] = positions[(bi + tid) * 2 + 1];
        pjx[tid] = positions[(bj + tid) * 2 + 0];
        pjy[tid] = positions[(bj + tid) * 2 + 1];
    }
    const float bb = b2[0];

    // W2 -> 16 float4 REGISTERS (loop-invariant; 64 VGPRs, affordable at 4 waves/SIMD)
    float4 wr[16];
#pragma unroll
    for (int q = 0; q < 16; ++q)
        wr[q] = ((const float4*)W2)[q];

    __syncthreads();

    const int ti = tid >> 4, tj = tid & 15;

    float acc00 = 0.f, acc01 = 0.f, acc10 = 0.f, acc11 = 0.f;
#pragma unroll
    for (int h = 0; h < Hn; h += 4) {
        const float4 a0 = *(const float4*)&shi[ti][h];
        const float4 a1 = *(const float4*)&shi[ti + 16][h];
        const float4 c0 = *(const float4*)&shj[tj][h];
        const float4 c1 = *(const float4*)&shj[tj + 16][h];
        const float4 w  = wr[h >> 2];
        gelu_acc(a0.x + c0.x, w.x, acc00); gelu_acc(a0.y + c0.y, w.y, acc00);
        gelu_acc(a0.z + c0.z, w.z, acc00); gelu_acc(a0.w + c0.w, w.w, acc00);
        gelu_acc(a0.x + c1.x, w.x, acc01); gelu_acc(a0.y + c1.y, w.y, acc01);
        gelu_acc(a0.z + c1.z, w.z, acc01); gelu_acc(a0.w + c1.w, w.w, acc01);
        gelu_acc(a1.x + c0.x, w.x, acc10); gelu_acc(a1.y + c0.y, w.y, acc10);
        gelu_acc(a1.z + c0.z, w.z, acc10); gelu_acc(a1.w + c0.w, w.w, acc10);
        gelu_acc(a1.x + c1.x, w.x, acc11); gelu_acc(a1.y + c1.y, w.y, acc11);
        gelu_acc(a1.z + c1.z, w.z, acc11); gelu_acc(a1.w + c1.w, w.w, acc11);
    }
    const float sd00 = acc00 + bb, sd01 = acc01 + bb;
    const float sd10 = acc10 + bb, sd11 = acc11 + bb;

    const float xi0 = pix[ti], yi0 = piy[ti], xi1 = pix[ti + 16], yi1 = piy[ti + 16];
    const float xj0 = pjx[tj], yj0 = pjy[tj], xj1 = pjx[tj + 16], yj1 = pjy[tj + 16];
    const float d200 = (xi0-xj0)*(xi0-xj0) + (yi0-yj0)*(yi0-yj0);
    const float d201 = (xi0-xj1)*(xi0-xj1) + (yi0-yj1)*(yi0-yj1);
    const float d210 = (xi1-xj0)*(xi1-xj0) + (yi1-yj0)*(yi1-yj0);
    const float d211 = (xi1-xj1)*(xi1-xj1) + (yi1-yj1)*(yi1-yj1);
    const float td00 = (d200 > 0.f) ? sqrtf(d200) : 0.f;
    const float td01 = (d201 > 0.f) ? sqrtf(d201) : 0.f;
    const float td10 = (d210 > 0.f) ? sqrtf(d210) : 0.f;
    const float td11 = (d211 > 0.f) ? sqrtf(d211) : 0.f;

    const int i0 = it * 32 + ti, i1 = i0 + 16;
    const int j0 = jt * 32 + tj, j1 = j0 + 16;
    out[((b * Kn) + i0) * Kn + j0] = sd00;
    out[((b * Kn) + i0) * Kn + j1] = sd01;
    out[((b * Kn) + i1) * Kn + j0] = sd10;
    out[((b * Kn) + i1) * Kn + j1] = sd11;

    // deterministic block reduce of squared error (4 outputs)
    float v = (sd00 - td00) * (sd00 - td00) + (sd01 - td01) * (sd01 - td01)
            + (sd10 - td10) * (sd10 - td10) + (sd11 - td11) * (sd11 - td11);
#pragma unroll
    for (int off = 32; off > 0; off >>= 1) v += __shfl_down(v, off);
    if ((tid & 63) == 0) wsum[tid >> 6] = v;
    __syncthreads();
    if (tid == 0) {
        const int bid = (b * gridDim.y + it) * gridDim.x + jt;
        partials[bid] = (wsum[0] + wsum[1]) + (wsum[2] + wsum[3]);
    }
}

// ---------------- Kernel C: final loss reduction (deterministic order) ----------------
__global__ __launch_bounds__(256) void kC(const float* __restrict__ partials,
                                          float* __restrict__ loss_out) {
    __shared__ float s[256];
    const int tid = threadIdx.x;
    const float4* p4 = (const float4*)partials;        // NBLK/4 = 256 float4
    const float4 x = p4[tid];
    s[tid] = (x.x + x.y) + (x.z + x.w);
    __syncthreads();
    for (int off = 128; off > 0; off >>= 1) {
        if (tid < off) s[tid] += s[tid + off];
        __syncthreads();
    }
    if (tid == 0)
        loss_out[0] = s[0] * (1.0f / (float)(Bn * Kn * Kn));
}

extern "C" void kernel_launch(void* const* d_in, const int* in_sizes, int n_in,
                              void* d_out, int out_size, void* d_ws, size_t ws_size,
                              hipStream_t stream) {
    const float* particles = (const float*)d_in[0];
    const float* positions = (const float*)d_in[1];
    const float* W1        = (const float*)d_in[2];
    const float* b1        = (const float*)d_in[3];
    const float* W2        = (const float*)d_in[4];
    const float* b2        = (const float*)d_in[5];

    float* out = (float*)d_out;                       // [B*K*K] sd, then [1] loss
    float* ws  = (float*)d_ws;
    float* hi       = ws;                             // B*K*H floats
    float* hj       = ws + Bn * Kn * Hn;
    float* partials = ws + 2 * Bn * Kn * Hn;          // NBLK floats

    kA<<<dim3((Bn * Kn) / 4), dim3(64), 0, stream>>>(particles, W1, b1, hi, hj);
    kB<<<dim3(Kn / 32, Kn / 32, Bn), dim3(256), 0, stream>>>(hi, hj, positions, W2, b2,
                                                             out, partials);
    kC<<<dim3(1), dim3(256), 0, stream>>>(partials, out + (size_t)Bn * Kn * Kn);
}